// Round 9
// baseline (214.998 us; speedup 1.0000x reference)
//
#include <hip/hip_runtime.h>
#include <cstdint>

// N=4096 windows, T=33, C=96, H=6, HD=16.
// ws layout v3:
//   qf  : fp32 q[n][h][t][d]              4096*3168 floats  = 51.9 MB
//         (attn overwrites each window's q region with its output, [t][c] fp32)
//   kvh : bf16 {k,v}[n][s][h][t][d]       4096*6336 ushorts = 51.9 MB
//         (dead after attn; conv_w_proj stashes proj_w B-fragments at its start)
// GEMMs: MFMA 16x16x32 bf16 split-precision (hi+lo): C = AhBh + AlBh + AhBl.
// Attn v8: 512-thread blocks, one THREAD PAIR per (head,row): even lane j=0..16,
// odd lane j=16..32 (odd's j=16 logit forced to -inf to avoid double count).
// Softmax max/sum and PV partials combined via __shfl_xor(.,1) — same wave,
// no extra barriers. K/V staged fp32 in LDS (37.9 KB) -> 4 blocks/CU -> 32 waves.

static constexpr int NWIN = 4096;
static constexpr int MROWS = NWIN * 33;          // 135168 = 1056*128
static constexpr float SCALE = 0.25f;            // HD^-0.5

using short8 = __attribute__((ext_vector_type(8))) short;
using f32x4  = __attribute__((ext_vector_type(4))) float;

__device__ __forceinline__ unsigned short f2bf(float f) {
  unsigned u = __float_as_uint(f);
  u += 0x7fffu + ((u >> 16) & 1u);
  return (unsigned short)(u >> 16);
}
__device__ __forceinline__ float bf2f(unsigned short h) {
  return __uint_as_float(((unsigned)h) << 16);
}
__device__ __forceinline__ float bflo(unsigned u) { return __uint_as_float(u << 16); }
__device__ __forceinline__ float bfhi(unsigned u) { return __uint_as_float(u & 0xffff0000u); }
__device__ __forceinline__ float dot4(const float4 a, const float4 b) {
  return a.x*b.x + a.y*b.y + a.z*b.z + a.w*b.w;
}
__device__ __forceinline__ void axpy4(float4& o, const float a, const float4 v) {
  o.x += a*v.x; o.y += a*v.y; o.z += a*v.z; o.w += a*v.w;
}

// ---------------- K0: qkv_w -> B-fragments in d_out ----------------
__global__ __launch_bounds__(256) void conv_w_qkv(
    const float* __restrict__ W, unsigned* __restrict__ frag) {
  const int fp = blockIdx.x;                     // 108 = 3 ksteps*18 cf*2 hl
  const int kstep = fp / 36;
  const int r = fp - kstep*36;
  const int cf = r >> 1, hl = r & 1;
  const int t = threadIdx.x, lane = t >> 2, d = t & 3;
  const int k = kstep*32 + (lane >> 4)*8 + d*2;
  const int n = cf*16 + (lane & 15);
  float w0 = W[k*288 + n], w1 = W[(k+1)*288 + n];
  if (hl) { w0 -= bf2f(f2bf(w0)); w1 -= bf2f(f2bf(w1)); }
  frag[fp*256 + t] = (unsigned)f2bf(w0) | ((unsigned)f2bf(w1) << 16);
}

// ---------------- K2b: proj_w -> B-fragments at start of (dead) kvh ----
__global__ __launch_bounds__(256) void conv_w_proj(
    const float* __restrict__ W, unsigned* __restrict__ frag) {
  const int fp = blockIdx.x;                     // 36 = 3 ksteps*6 cf*2 hl
  const int kstep = fp / 12;
  const int r = fp - kstep*12;
  const int cf = r >> 1, hl = r & 1;
  const int t = threadIdx.x, lane = t >> 2, d = t & 3;
  const int k = kstep*32 + (lane >> 4)*8 + d*2;
  const int n = cf*16 + (lane & 15);
  float w0 = W[k*96 + n], w1 = W[(k+1)*96 + n];
  if (hl) { w0 -= bf2f(f2bf(w0)); w1 -= bf2f(f2bf(w1)); }
  frag[fp*256 + t] = (unsigned)f2bf(w0) | ((unsigned)f2bf(w1) << 16);
}

// ---------------- K1: QKV projection, split-bf16 MFMA ----------------
// grid (1056, 3), block 256 (4 waves). s: 0=q (fp32 out), 1=k, 2=v (bf16 out).
__global__ __launch_bounds__(256) void qkv_mfma(
    const float* __restrict__ A, const unsigned* __restrict__ frag,
    const float* __restrict__ bias, float* __restrict__ qf,
    unsigned short* __restrict__ kvh) {
  __shared__ __align__(16) unsigned short sAh[128*104];
  __shared__ __align__(16) unsigned short sAl[128*104];
  const int tid = threadIdx.x;
  const int w = tid >> 6, l = tid & 63;
  const int m0 = blockIdx.x * 128;
  const int s = blockIdx.y;
  for (int idx = tid; idx < 3072; idx += 256) {
    const int row = idx / 24, q = idx - row*24;
    const float4 v = *(const float4*)(A + (size_t)(m0+row)*96 + q*4);
    ushort4 hv, lv;
    hv.x = f2bf(v.x); hv.y = f2bf(v.y); hv.z = f2bf(v.z); hv.w = f2bf(v.w);
    lv.x = f2bf(v.x - bf2f(hv.x)); lv.y = f2bf(v.y - bf2f(hv.y));
    lv.z = f2bf(v.z - bf2f(hv.z)); lv.w = f2bf(v.w - bf2f(hv.w));
    *(ushort4*)&sAh[row*104 + q*4] = hv;
    *(ushort4*)&sAl[row*104 + q*4] = lv;
  }
  __syncthreads();
  f32x4 acc[2][6];
  #pragma unroll
  for (int rf = 0; rf < 2; ++rf)
    #pragma unroll
    for (int cf = 0; cf < 6; ++cf) acc[rf][cf] = (f32x4){0.f,0.f,0.f,0.f};

  #pragma unroll
  for (int kstep = 0; kstep < 3; ++kstep) {
    short8 bh[6], bl[6];
    #pragma unroll
    for (int cf = 0; cf < 6; ++cf) {
      const int fp = (kstep*18 + s*6 + cf)*2;
      bh[cf] = *(const short8*)((const char*)frag + (size_t)fp*1024 + l*16);
      bl[cf] = *(const short8*)((const char*)frag + (size_t)fp*1024 + 1024 + l*16);
    }
    #pragma unroll
    for (int rf = 0; rf < 2; ++rf) {
      const int row = w*32 + rf*16 + (l & 15);
      const int off = row*104 + kstep*32 + (l >> 4)*8;
      const short8 ah = *(const short8*)&sAh[off];
      const short8 al = *(const short8*)&sAl[off];
      #pragma unroll
      for (int cf = 0; cf < 6; ++cf) {
        acc[rf][cf] = __builtin_amdgcn_mfma_f32_16x16x32_bf16(ah, bh[cf], acc[rf][cf], 0,0,0);
        acc[rf][cf] = __builtin_amdgcn_mfma_f32_16x16x32_bf16(al, bh[cf], acc[rf][cf], 0,0,0);
        acc[rf][cf] = __builtin_amdgcn_mfma_f32_16x16x32_bf16(ah, bl[cf], acc[rf][cf], 0,0,0);
      }
    }
  }
  const int col = l & 15;
  if (s == 0) {
    #pragma unroll
    for (int cf = 0; cf < 6; ++cf) {
      const float bv = bias[cf*16 + col];
      #pragma unroll
      for (int rf = 0; rf < 2; ++rf)
        #pragma unroll
        for (int r = 0; r < 4; ++r) {
          const int m = m0 + w*32 + rf*16 + (l >> 4)*4 + r;
          const int n = m / 33, t = m - n*33;
          qf[(size_t)n*3168 + cf*528 + t*16 + col] = (acc[rf][cf][r] + bv)*SCALE;
        }
    }
  } else {
    unsigned short* kvs = kvh + (size_t)(s-1)*3168;
    #pragma unroll
    for (int cf = 0; cf < 6; ++cf) {
      const float bv = bias[s*96 + cf*16 + col];
      #pragma unroll
      for (int rf = 0; rf < 2; ++rf)
        #pragma unroll
        for (int r = 0; r < 4; ++r) {
          const int m = m0 + w*32 + rf*16 + (l >> 4)*4 + r;
          const int n = m / 33, t = m - n*33;
          kvs[(size_t)n*6336 + cf*528 + t*16 + col] = f2bf(acc[rf][cf][r] + bv);
        }
    }
  }
}

// ---------------- K2: per-window attention (v8, thread-pair split) ------
// grid 4096, block 512. Pair pr = tid>>1 -> (h, i); half = tid&1 handles
// j = 16*half + jj (jj=0..16); odd half's j=16 logit set to -inf.
__global__ __launch_bounds__(512) void attn_kernel(
    float* __restrict__ qf, const unsigned short* __restrict__ kvh,
    const int* __restrict__ rel, const float* __restrict__ mask,
    const float* __restrict__ rpet) {
  __shared__ __align__(16) float sKf[3168];           // 12672 B
  __shared__ __align__(16) float sVf[3168];           // 12672 B
  __shared__ float sMask[1089];                       //  4356 B
  __shared__ unsigned sRelP[1056];                    //  4224 B
  __shared__ float sRPE[918];                         //  3672 B
  const int tid = threadIdx.x;
  const int n = blockIdx.x;
  const uint4* kvb = (const uint4*)(kvh + (size_t)n*6336);
  // K and V: 396 uint4 each, bf16 -> fp32 exact widen
  for (int idx = tid; idx < 396; idx += 512) {
    const uint4 u = kvb[idx];
    float4 a, b;
    a.x = bflo(u.x); a.y = bfhi(u.x); a.z = bflo(u.y); a.w = bfhi(u.y);
    b.x = bflo(u.z); b.y = bfhi(u.z); b.z = bflo(u.w); b.w = bfhi(u.w);
    *(float4*)&sKf[idx*8]     = a;
    *(float4*)&sKf[idx*8 + 4] = b;
    const uint4 w = kvb[396 + idx];
    float4 c, d;
    c.x = bflo(w.x); c.y = bfhi(w.x); c.z = bflo(w.y); c.w = bfhi(w.y);
    d.x = bflo(w.z); d.y = bfhi(w.z); d.z = bflo(w.w); d.w = bfhi(w.w);
    *(float4*)&sVf[idx*8]     = c;
    *(float4*)&sVf[idx*8 + 4] = d;
  }
  {
    const int* rb = rel + (size_t)n*3072;
    for (int p = tid; p < 1024; p += 512) {
      const int b = p*3;
      sRelP[(p >> 5)*33 + (p & 31)] =
          (unsigned)rb[b] | ((unsigned)rb[b+1] << 8) | ((unsigned)rb[b+2] << 16);
    }
  }
  for (int idx = tid; idx < 1089; idx += 512)
    sMask[idx] = mask[(size_t)n*1089 + idx];
  for (int idx = tid; idx < 918; idx += 512)
    sRPE[idx] = rpet[idx];

  const int pr = tid >> 1, half = tid & 1;
  float4 q0, q1, q2, q3;
  int h = 0, i = 0;
  if (pr < 198) {
    h = pr / 33; i = pr - h*33;
    const float4* qb = (const float4*)(qf + (size_t)n*3168 + h*528 + i*16);
    q0 = qb[0]; q1 = qb[1]; q2 = qb[2]; q3 = qb[3];   // q read BEFORE barrier
  }
  __syncthreads();
  if (pr < 198) {
    const float* rph = sRPE + h;
    const int j0 = half << 4;                          // 0 or 16
    float p[17];
    #pragma unroll
    for (int jj = 0; jj < 17; ++jj) {
      const int j = j0 + jj;
      const float4* kr = (const float4*)&sKf[(h*33 + j)*16];
      float lo = dot4(q0,kr[0]) + dot4(q1,kr[1]) + dot4(q2,kr[2]) + dot4(q3,kr[3]);
      lo += sMask[i*33 + j];
      if (i > 0 && j > 0) {
        const unsigned pk = sRelP[(i-1)*33 + (j-1)];
        lo += rph[(pk & 0xffu)*6]
            + rph[((pk >> 8) & 0xffu)*6 + 306]
            + rph[((pk >> 16) & 0xffu)*6 + 612];
      }
      p[jj] = lo;
    }
    if (half) p[0] = -3.4e38f;                         // j=16 counted by even lane only
    float mx = p[0];
    #pragma unroll
    for (int jj = 1; jj < 17; ++jj) mx = fmaxf(mx, p[jj]);
    mx = fmaxf(mx, __shfl_xor(mx, 1));                 // pair-wide max
    float ssum = 0.f;
    #pragma unroll
    for (int jj = 0; jj < 17; ++jj) { p[jj] = __expf(p[jj] - mx); ssum += p[jj]; }
    ssum += __shfl_xor(ssum, 1);                       // pair-wide sum
    const float inv = 1.0f / ssum;
    float4 o0 = make_float4(0.f,0.f,0.f,0.f), o1 = o0, o2 = o0, o3 = o0;
    #pragma unroll
    for (int jj = 0; jj < 17; ++jj) {
      const float pj = p[jj];
      const float4* vr = (const float4*)&sVf[(h*33 + j0 + jj)*16];
      axpy4(o0, pj, vr[0]); axpy4(o1, pj, vr[1]);
      axpy4(o2, pj, vr[2]); axpy4(o3, pj, vr[3]);
    }
    // combine pair partials (each gets full sums), then each half writes 8 dims
    o0.x += __shfl_xor(o0.x,1); o0.y += __shfl_xor(o0.y,1);
    o0.z += __shfl_xor(o0.z,1); o0.w += __shfl_xor(o0.w,1);
    o1.x += __shfl_xor(o1.x,1); o1.y += __shfl_xor(o1.y,1);
    o1.z += __shfl_xor(o1.z,1); o1.w += __shfl_xor(o1.w,1);
    o2.x += __shfl_xor(o2.x,1); o2.y += __shfl_xor(o2.y,1);
    o2.z += __shfl_xor(o2.z,1); o2.w += __shfl_xor(o2.w,1);
    o3.x += __shfl_xor(o3.x,1); o3.y += __shfl_xor(o3.y,1);
    o3.z += __shfl_xor(o3.z,1); o3.w += __shfl_xor(o3.w,1);
    float* op = qf + (size_t)n*3168 + (size_t)i*96 + h*16;
    if (!half) {
      o0.x*=inv; o0.y*=inv; o0.z*=inv; o0.w*=inv;
      o1.x*=inv; o1.y*=inv; o1.z*=inv; o1.w*=inv;
      *(float4*)(op + 0) = o0; *(float4*)(op + 4) = o1;
    } else {
      o2.x*=inv; o2.y*=inv; o2.z*=inv; o2.w*=inv;
      o3.x*=inv; o3.y*=inv; o3.z*=inv; o3.w*=inv;
      *(float4*)(op + 8) = o2; *(float4*)(op + 12) = o3;
    }
  }
}

// ---------------- K3: output projection, split-bf16 MFMA ----------------
// grid 1056, block 256. A = attn output in qf; B-frags at start of kvh.
__global__ __launch_bounds__(256) void proj_mfma(
    const float* __restrict__ qf, const unsigned* __restrict__ frag,
    const float* __restrict__ bias, float* __restrict__ out) {
  __shared__ __align__(16) unsigned short sAh[128*104];
  __shared__ __align__(16) unsigned short sAl[128*104];
  const int tid = threadIdx.x;
  const int w = tid >> 6, l = tid & 63;
  const int m0 = blockIdx.x * 128;
  for (int idx = tid; idx < 3072; idx += 256) {
    const int row = idx / 24, q = idx - row*24;
    const int m = m0 + row;
    const int n = m / 33, t = m - n*33;
    const float4 v = *(const float4*)(qf + (size_t)n*3168 + t*96 + q*4);
    ushort4 hv, lv;
    hv.x = f2bf(v.x); hv.y = f2bf(v.y); hv.z = f2bf(v.z); hv.w = f2bf(v.w);
    lv.x = f2bf(v.x - bf2f(hv.x)); lv.y = f2bf(v.y - bf2f(hv.y));
    lv.z = f2bf(v.z - bf2f(hv.z)); lv.w = f2bf(v.w - bf2f(hv.w));
    *(ushort4*)&sAh[row*104 + q*4] = hv;
    *(ushort4*)&sAl[row*104 + q*4] = lv;
  }
  __syncthreads();
  f32x4 acc[2][6];
  #pragma unroll
  for (int rf = 0; rf < 2; ++rf)
    #pragma unroll
    for (int cf = 0; cf < 6; ++cf) acc[rf][cf] = (f32x4){0.f,0.f,0.f,0.f};

  #pragma unroll
  for (int kstep = 0; kstep < 3; ++kstep) {
    short8 bh[6], bl[6];
    #pragma unroll
    for (int cf = 0; cf < 6; ++cf) {
      const int fph = kstep*12 + cf*2;
      bh[cf] = *(const short8*)(frag + fph*256 + l*4);
      bl[cf] = *(const short8*)(frag + (fph+1)*256 + l*4);
    }
    #pragma unroll
    for (int rf = 0; rf < 2; ++rf) {
      const int row = w*32 + rf*16 + (l & 15);
      const int off = row*104 + kstep*32 + (l >> 4)*8;
      const short8 ah = *(const short8*)&sAh[off];
      const short8 al = *(const short8*)&sAl[off];
      #pragma unroll
      for (int cf = 0; cf < 6; ++cf) {
        acc[rf][cf] = __builtin_amdgcn_mfma_f32_16x16x32_bf16(ah, bh[cf], acc[rf][cf], 0,0,0);
        acc[rf][cf] = __builtin_amdgcn_mfma_f32_16x16x32_bf16(al, bh[cf], acc[rf][cf], 0,0,0);
        acc[rf][cf] = __builtin_amdgcn_mfma_f32_16x16x32_bf16(ah, bl[cf], acc[rf][cf], 0,0,0);
      }
    }
  }
  const int col = l & 15;
  #pragma unroll
  for (int cf = 0; cf < 6; ++cf) {
    const float bv = bias[cf*16 + col];
    #pragma unroll
    for (int rf = 0; rf < 2; ++rf)
      #pragma unroll
      for (int r = 0; r < 4; ++r) {
        const int m = m0 + w*32 + rf*16 + (l >> 4)*4 + r;
        out[(size_t)m*96 + cf*16 + col] = acc[rf][cf][r] + bv;
      }
  }
}

extern "C" void kernel_launch(void* const* d_in, const int* in_sizes, int n_in,
                              void* d_out, int out_size, void* d_ws, size_t ws_size,
                              hipStream_t stream) {
  const float* data   = (const float*)d_in[0];
  const int*   rel    = (const int*)  d_in[1];
  const float* mask   = (const float*)d_in[2];
  const float* qkv_w  = (const float*)d_in[3];
  const float* qkv_b  = (const float*)d_in[4];
  const float* proj_w = (const float*)d_in[5];
  const float* proj_b = (const float*)d_in[6];
  const float* rpet   = (const float*)d_in[7];
  float* qf = (float*)d_ws;                              // 51.9 MB
  unsigned short* kvh = (unsigned short*)(qf + (size_t)NWIN*3168);  // 51.9 MB
  float* out = (float*)d_out;

  conv_w_qkv <<<dim3(108),         256, 0, stream>>>(qkv_w, (unsigned*)d_out);
  qkv_mfma   <<<dim3(MROWS/128,3), 256, 0, stream>>>(data, (const unsigned*)d_out, qkv_b, qf, kvh);
  attn_kernel<<<dim3(NWIN),        512, 0, stream>>>(qf, kvh, rel, mask, rpet);
  conv_w_proj<<<dim3(36),          256, 0, stream>>>(proj_w, (unsigned*)kvh);
  proj_mfma  <<<dim3(MROWS/128),   256, 0, stream>>>(qf, (const unsigned*)kvh, proj_b, out);
}

// Round 10
// 203.933 us; speedup vs baseline: 1.0543x; 1.0543x over previous
//
#include <hip/hip_runtime.h>
#include <cstdint>

// N=4096 windows, T=33, C=96, H=6, HD=16.
// ws layout v3:
//   qf  : fp32 q[n][h][t][d]              4096*3168 floats  = 51.9 MB
//         (attn overwrites each window's q region with its output, [t][c] fp32)
//   kvh : bf16 {k,v}[n][s][h][t][d]       4096*6336 ushorts = 51.9 MB
//         (dead after attn; conv_w_proj stashes proj_w B-fragments at its start)
// GEMMs: MFMA 16x16x32 bf16 split-precision (hi+lo): C = AhBh + AlBh + AhBl.
// Attn v9: thread-pair split with INTERLEAVED j (even lane: even j, odd lane:
// odd j). v8's j/j+16 split put pair lanes 1024B apart in LDS = same bank on
// every ds_read_b128 (conflicts 6.3M->27.9M, +45us). Adjacent rows (64B) hit
// disjoint bank halves -> conflict-free. Pair reductions via __shfl_xor(.,1).

static constexpr int NWIN = 4096;
static constexpr int MROWS = NWIN * 33;          // 135168 = 1056*128
static constexpr float SCALE = 0.25f;            // HD^-0.5

using short8 = __attribute__((ext_vector_type(8))) short;
using f32x4  = __attribute__((ext_vector_type(4))) float;

__device__ __forceinline__ unsigned short f2bf(float f) {
  unsigned u = __float_as_uint(f);
  u += 0x7fffu + ((u >> 16) & 1u);
  return (unsigned short)(u >> 16);
}
__device__ __forceinline__ float bf2f(unsigned short h) {
  return __uint_as_float(((unsigned)h) << 16);
}
__device__ __forceinline__ float bflo(unsigned u) { return __uint_as_float(u << 16); }
__device__ __forceinline__ float bfhi(unsigned u) { return __uint_as_float(u & 0xffff0000u); }
__device__ __forceinline__ float dot4(const float4 a, const float4 b) {
  return a.x*b.x + a.y*b.y + a.z*b.z + a.w*b.w;
}
__device__ __forceinline__ void axpy4(float4& o, const float a, const float4 v) {
  o.x += a*v.x; o.y += a*v.y; o.z += a*v.z; o.w += a*v.w;
}

// ---------------- K0: qkv_w -> B-fragments in d_out ----------------
__global__ __launch_bounds__(256) void conv_w_qkv(
    const float* __restrict__ W, unsigned* __restrict__ frag) {
  const int fp = blockIdx.x;                     // 108 = 3 ksteps*18 cf*2 hl
  const int kstep = fp / 36;
  const int r = fp - kstep*36;
  const int cf = r >> 1, hl = r & 1;
  const int t = threadIdx.x, lane = t >> 2, d = t & 3;
  const int k = kstep*32 + (lane >> 4)*8 + d*2;
  const int n = cf*16 + (lane & 15);
  float w0 = W[k*288 + n], w1 = W[(k+1)*288 + n];
  if (hl) { w0 -= bf2f(f2bf(w0)); w1 -= bf2f(f2bf(w1)); }
  frag[fp*256 + t] = (unsigned)f2bf(w0) | ((unsigned)f2bf(w1) << 16);
}

// ---------------- K2b: proj_w -> B-fragments at start of (dead) kvh ----
__global__ __launch_bounds__(256) void conv_w_proj(
    const float* __restrict__ W, unsigned* __restrict__ frag) {
  const int fp = blockIdx.x;                     // 36 = 3 ksteps*6 cf*2 hl
  const int kstep = fp / 12;
  const int r = fp - kstep*12;
  const int cf = r >> 1, hl = r & 1;
  const int t = threadIdx.x, lane = t >> 2, d = t & 3;
  const int k = kstep*32 + (lane >> 4)*8 + d*2;
  const int n = cf*16 + (lane & 15);
  float w0 = W[k*96 + n], w1 = W[(k+1)*96 + n];
  if (hl) { w0 -= bf2f(f2bf(w0)); w1 -= bf2f(f2bf(w1)); }
  frag[fp*256 + t] = (unsigned)f2bf(w0) | ((unsigned)f2bf(w1) << 16);
}

// ---------------- K1: QKV projection, split-bf16 MFMA ----------------
// grid (1056, 3), block 256 (4 waves). s: 0=q (fp32 out), 1=k, 2=v (bf16 out).
__global__ __launch_bounds__(256) void qkv_mfma(
    const float* __restrict__ A, const unsigned* __restrict__ frag,
    const float* __restrict__ bias, float* __restrict__ qf,
    unsigned short* __restrict__ kvh) {
  __shared__ __align__(16) unsigned short sAh[128*104];
  __shared__ __align__(16) unsigned short sAl[128*104];
  const int tid = threadIdx.x;
  const int w = tid >> 6, l = tid & 63;
  const int m0 = blockIdx.x * 128;
  const int s = blockIdx.y;
  for (int idx = tid; idx < 3072; idx += 256) {
    const int row = idx / 24, q = idx - row*24;
    const float4 v = *(const float4*)(A + (size_t)(m0+row)*96 + q*4);
    ushort4 hv, lv;
    hv.x = f2bf(v.x); hv.y = f2bf(v.y); hv.z = f2bf(v.z); hv.w = f2bf(v.w);
    lv.x = f2bf(v.x - bf2f(hv.x)); lv.y = f2bf(v.y - bf2f(hv.y));
    lv.z = f2bf(v.z - bf2f(hv.z)); lv.w = f2bf(v.w - bf2f(hv.w));
    *(ushort4*)&sAh[row*104 + q*4] = hv;
    *(ushort4*)&sAl[row*104 + q*4] = lv;
  }
  __syncthreads();
  f32x4 acc[2][6];
  #pragma unroll
  for (int rf = 0; rf < 2; ++rf)
    #pragma unroll
    for (int cf = 0; cf < 6; ++cf) acc[rf][cf] = (f32x4){0.f,0.f,0.f,0.f};

  #pragma unroll
  for (int kstep = 0; kstep < 3; ++kstep) {
    short8 bh[6], bl[6];
    #pragma unroll
    for (int cf = 0; cf < 6; ++cf) {
      const int fp = (kstep*18 + s*6 + cf)*2;
      bh[cf] = *(const short8*)((const char*)frag + (size_t)fp*1024 + l*16);
      bl[cf] = *(const short8*)((const char*)frag + (size_t)fp*1024 + 1024 + l*16);
    }
    #pragma unroll
    for (int rf = 0; rf < 2; ++rf) {
      const int row = w*32 + rf*16 + (l & 15);
      const int off = row*104 + kstep*32 + (l >> 4)*8;
      const short8 ah = *(const short8*)&sAh[off];
      const short8 al = *(const short8*)&sAl[off];
      #pragma unroll
      for (int cf = 0; cf < 6; ++cf) {
        acc[rf][cf] = __builtin_amdgcn_mfma_f32_16x16x32_bf16(ah, bh[cf], acc[rf][cf], 0,0,0);
        acc[rf][cf] = __builtin_amdgcn_mfma_f32_16x16x32_bf16(al, bh[cf], acc[rf][cf], 0,0,0);
        acc[rf][cf] = __builtin_amdgcn_mfma_f32_16x16x32_bf16(ah, bl[cf], acc[rf][cf], 0,0,0);
      }
    }
  }
  const int col = l & 15;
  if (s == 0) {
    #pragma unroll
    for (int cf = 0; cf < 6; ++cf) {
      const float bv = bias[cf*16 + col];
      #pragma unroll
      for (int rf = 0; rf < 2; ++rf)
        #pragma unroll
        for (int r = 0; r < 4; ++r) {
          const int m = m0 + w*32 + rf*16 + (l >> 4)*4 + r;
          const int n = m / 33, t = m - n*33;
          qf[(size_t)n*3168 + cf*528 + t*16 + col] = (acc[rf][cf][r] + bv)*SCALE;
        }
    }
  } else {
    unsigned short* kvs = kvh + (size_t)(s-1)*3168;
    #pragma unroll
    for (int cf = 0; cf < 6; ++cf) {
      const float bv = bias[s*96 + cf*16 + col];
      #pragma unroll
      for (int rf = 0; rf < 2; ++rf)
        #pragma unroll
        for (int r = 0; r < 4; ++r) {
          const int m = m0 + w*32 + rf*16 + (l >> 4)*4 + r;
          const int n = m / 33, t = m - n*33;
          kvs[(size_t)n*6336 + cf*528 + t*16 + col] = f2bf(acc[rf][cf][r] + bv);
        }
    }
  }
}

// ---------------- K2: per-window attention (v9, interleaved pair split) --
// grid 4096, block 512. Pair pr = tid>>1 -> (h, i); half = tid&1.
// Lane handles j = 2*jj + half (jj=0..16); odd lane's jj=16 is dead (-inf).
__global__ __launch_bounds__(512) void attn_kernel(
    float* __restrict__ qf, const unsigned short* __restrict__ kvh,
    const int* __restrict__ rel, const float* __restrict__ mask,
    const float* __restrict__ rpet) {
  __shared__ __align__(16) float sKf[3168];           // 12672 B
  __shared__ __align__(16) float sVf[3168];           // 12672 B
  __shared__ float sMask[1089];                       //  4356 B
  __shared__ unsigned sRelP[1056];                    //  4224 B
  __shared__ float sRPE[918];                         //  3672 B
  const int tid = threadIdx.x;
  const int n = blockIdx.x;
  const uint4* kvb = (const uint4*)(kvh + (size_t)n*6336);
  // K and V: 396 uint4 each, bf16 -> fp32 exact widen
  for (int idx = tid; idx < 396; idx += 512) {
    const uint4 u = kvb[idx];
    float4 a, b;
    a.x = bflo(u.x); a.y = bfhi(u.x); a.z = bflo(u.y); a.w = bfhi(u.y);
    b.x = bflo(u.z); b.y = bfhi(u.z); b.z = bflo(u.w); b.w = bfhi(u.w);
    *(float4*)&sKf[idx*8]     = a;
    *(float4*)&sKf[idx*8 + 4] = b;
    const uint4 w = kvb[396 + idx];
    float4 c, d;
    c.x = bflo(w.x); c.y = bfhi(w.x); c.z = bflo(w.y); c.w = bfhi(w.y);
    d.x = bflo(w.z); d.y = bfhi(w.z); d.z = bflo(w.w); d.w = bfhi(w.w);
    *(float4*)&sVf[idx*8]     = c;
    *(float4*)&sVf[idx*8 + 4] = d;
  }
  {
    const int* rb = rel + (size_t)n*3072;
    for (int p = tid; p < 1024; p += 512) {
      const int b = p*3;
      sRelP[(p >> 5)*33 + (p & 31)] =
          (unsigned)rb[b] | ((unsigned)rb[b+1] << 8) | ((unsigned)rb[b+2] << 16);
    }
  }
  for (int idx = tid; idx < 1089; idx += 512)
    sMask[idx] = mask[(size_t)n*1089 + idx];
  for (int idx = tid; idx < 918; idx += 512)
    sRPE[idx] = rpet[idx];

  const int pr = tid >> 1, half = tid & 1;
  float4 q0, q1, q2, q3;
  int h = 0, i = 0;
  if (pr < 198) {
    h = pr / 33; i = pr - h*33;
    const float4* qb = (const float4*)(qf + (size_t)n*3168 + h*528 + i*16);
    q0 = qb[0]; q1 = qb[1]; q2 = qb[2]; q3 = qb[3];   // q read BEFORE barrier
  }
  __syncthreads();
  if (pr < 198) {
    const float* rph = sRPE + h;
    float p[17];
    #pragma unroll
    for (int jj = 0; jj < 17; ++jj) {
      int j = (jj << 1) + half;                        // interleaved: even/odd j
      const bool dead = (j > 32);                      // odd lane's jj=16
      if (dead) j = 32;                                // safe in-bounds read
      const float4* kr = (const float4*)&sKf[(h*33 + j)*16];
      float lo = dot4(q0,kr[0]) + dot4(q1,kr[1]) + dot4(q2,kr[2]) + dot4(q3,kr[3]);
      lo += sMask[i*33 + j];
      if (i > 0 && j > 0) {
        const unsigned pk = sRelP[(i-1)*33 + (j-1)];
        lo += rph[(pk & 0xffu)*6]
            + rph[((pk >> 8) & 0xffu)*6 + 306]
            + rph[((pk >> 16) & 0xffu)*6 + 612];
      }
      p[jj] = dead ? -3.4e38f : lo;
    }
    float mx = p[0];
    #pragma unroll
    for (int jj = 1; jj < 17; ++jj) mx = fmaxf(mx, p[jj]);
    mx = fmaxf(mx, __shfl_xor(mx, 1));                 // pair-wide max
    float ssum = 0.f;
    #pragma unroll
    for (int jj = 0; jj < 17; ++jj) { p[jj] = __expf(p[jj] - mx); ssum += p[jj]; }
    ssum += __shfl_xor(ssum, 1);                       // pair-wide sum
    const float inv = 1.0f / ssum;
    float4 o0 = make_float4(0.f,0.f,0.f,0.f), o1 = o0, o2 = o0, o3 = o0;
    #pragma unroll
    for (int jj = 0; jj < 17; ++jj) {
      int j = (jj << 1) + half;
      if (j > 32) j = 32;                              // p[16]=0 for odd: no-op
      const float pj = p[jj];
      const float4* vr = (const float4*)&sVf[(h*33 + j)*16];
      axpy4(o0, pj, vr[0]); axpy4(o1, pj, vr[1]);
      axpy4(o2, pj, vr[2]); axpy4(o3, pj, vr[3]);
    }
    // combine pair partials, then each half writes 8 dims
    o0.x += __shfl_xor(o0.x,1); o0.y += __shfl_xor(o0.y,1);
    o0.z += __shfl_xor(o0.z,1); o0.w += __shfl_xor(o0.w,1);
    o1.x += __shfl_xor(o1.x,1); o1.y += __shfl_xor(o1.y,1);
    o1.z += __shfl_xor(o1.z,1); o1.w += __shfl_xor(o1.w,1);
    o2.x += __shfl_xor(o2.x,1); o2.y += __shfl_xor(o2.y,1);
    o2.z += __shfl_xor(o2.z,1); o2.w += __shfl_xor(o2.w,1);
    o3.x += __shfl_xor(o3.x,1); o3.y += __shfl_xor(o3.y,1);
    o3.z += __shfl_xor(o3.z,1); o3.w += __shfl_xor(o3.w,1);
    float* op = qf + (size_t)n*3168 + (size_t)i*96 + h*16;
    if (!half) {
      o0.x*=inv; o0.y*=inv; o0.z*=inv; o0.w*=inv;
      o1.x*=inv; o1.y*=inv; o1.z*=inv; o1.w*=inv;
      *(float4*)(op + 0) = o0; *(float4*)(op + 4) = o1;
    } else {
      o2.x*=inv; o2.y*=inv; o2.z*=inv; o2.w*=inv;
      o3.x*=inv; o3.y*=inv; o3.z*=inv; o3.w*=inv;
      *(float4*)(op + 8) = o2; *(float4*)(op + 12) = o3;
    }
  }
}

// ---------------- K3: output projection, split-bf16 MFMA ----------------
// grid 1056, block 256. A = attn output in qf; B-frags at start of kvh.
__global__ __launch_bounds__(256) void proj_mfma(
    const float* __restrict__ qf, const unsigned* __restrict__ frag,
    const float* __restrict__ bias, float* __restrict__ out) {
  __shared__ __align__(16) unsigned short sAh[128*104];
  __shared__ __align__(16) unsigned short sAl[128*104];
  const int tid = threadIdx.x;
  const int w = tid >> 6, l = tid & 63;
  const int m0 = blockIdx.x * 128;
  for (int idx = tid; idx < 3072; idx += 256) {
    const int row = idx / 24, q = idx - row*24;
    const int m = m0 + row;
    const int n = m / 33, t = m - n*33;
    const float4 v = *(const float4*)(qf + (size_t)n*3168 + t*96 + q*4);
    ushort4 hv, lv;
    hv.x = f2bf(v.x); hv.y = f2bf(v.y); hv.z = f2bf(v.z); hv.w = f2bf(v.w);
    lv.x = f2bf(v.x - bf2f(hv.x)); lv.y = f2bf(v.y - bf2f(hv.y));
    lv.z = f2bf(v.z - bf2f(hv.z)); lv.w = f2bf(v.w - bf2f(hv.w));
    *(ushort4*)&sAh[row*104 + q*4] = hv;
    *(ushort4*)&sAl[row*104 + q*4] = lv;
  }
  __syncthreads();
  f32x4 acc[2][6];
  #pragma unroll
  for (int rf = 0; rf < 2; ++rf)
    #pragma unroll
    for (int cf = 0; cf < 6; ++cf) acc[rf][cf] = (f32x4){0.f,0.f,0.f,0.f};

  #pragma unroll
  for (int kstep = 0; kstep < 3; ++kstep) {
    short8 bh[6], bl[6];
    #pragma unroll
    for (int cf = 0; cf < 6; ++cf) {
      const int fph = kstep*12 + cf*2;
      bh[cf] = *(const short8*)(frag + fph*256 + l*4);
      bl[cf] = *(const short8*)(frag + (fph+1)*256 + l*4);
    }
    #pragma unroll
    for (int rf = 0; rf < 2; ++rf) {
      const int row = w*32 + rf*16 + (l & 15);
      const int off = row*104 + kstep*32 + (l >> 4)*8;
      const short8 ah = *(const short8*)&sAh[off];
      const short8 al = *(const short8*)&sAl[off];
      #pragma unroll
      for (int cf = 0; cf < 6; ++cf) {
        acc[rf][cf] = __builtin_amdgcn_mfma_f32_16x16x32_bf16(ah, bh[cf], acc[rf][cf], 0,0,0);
        acc[rf][cf] = __builtin_amdgcn_mfma_f32_16x16x32_bf16(al, bh[cf], acc[rf][cf], 0,0,0);
        acc[rf][cf] = __builtin_amdgcn_mfma_f32_16x16x32_bf16(ah, bl[cf], acc[rf][cf], 0,0,0);
      }
    }
  }
  const int col = l & 15;
  #pragma unroll
  for (int cf = 0; cf < 6; ++cf) {
    const float bv = bias[cf*16 + col];
    #pragma unroll
    for (int rf = 0; rf < 2; ++rf)
      #pragma unroll
      for (int r = 0; r < 4; ++r) {
        const int m = m0 + w*32 + rf*16 + (l >> 4)*4 + r;
        out[(size_t)m*96 + cf*16 + col] = acc[rf][cf][r] + bv;
      }
  }
}

extern "C" void kernel_launch(void* const* d_in, const int* in_sizes, int n_in,
                              void* d_out, int out_size, void* d_ws, size_t ws_size,
                              hipStream_t stream) {
  const float* data   = (const float*)d_in[0];
  const int*   rel    = (const int*)  d_in[1];
  const float* mask   = (const float*)d_in[2];
  const float* qkv_w  = (const float*)d_in[3];
  const float* qkv_b  = (const float*)d_in[4];
  const float* proj_w = (const float*)d_in[5];
  const float* proj_b = (const float*)d_in[6];
  const float* rpet   = (const float*)d_in[7];
  float* qf = (float*)d_ws;                              // 51.9 MB
  unsigned short* kvh = (unsigned short*)(qf + (size_t)NWIN*3168);  // 51.9 MB
  float* out = (float*)d_out;

  conv_w_qkv <<<dim3(108),         256, 0, stream>>>(qkv_w, (unsigned*)d_out);
  qkv_mfma   <<<dim3(MROWS/128,3), 256, 0, stream>>>(data, (const unsigned*)d_out, qkv_b, qf, kvh);
  attn_kernel<<<dim3(NWIN),        512, 0, stream>>>(qf, kvh, rel, mask, rpet);
  conv_w_proj<<<dim3(36),          256, 0, stream>>>(proj_w, (unsigned*)kvh);
  proj_mfma  <<<dim3(MROWS/128),   256, 0, stream>>>(qf, (const unsigned*)kvh, proj_b, out);
}

// Round 11
// 178.718 us; speedup vs baseline: 1.2030x; 1.1411x over previous
//
#include <hip/hip_runtime.h>
#include <cstdint>

// N=4096 windows, T=33, C=96, H=6, HD=16.
// ws layout v3:
//   qf  : fp32 q[n][h][t][d]              4096*3168 floats  = 51.9 MB
//         (attn overwrites each window's q region with its output, [t][c] fp32)
//   kvh : bf16 {k,v}[n][s][h][t][d]       4096*6336 ushorts = 51.9 MB
//         (dead after attn; conv_w_proj stashes proj_w B-fragments at its start)
// GEMMs: MFMA 16x16x32 bf16 split-precision (hi+lo): C = AhBh + AlBh + AhBl.
// Attn v10: v7 structure (thread=(h,i), K/V fp32 in LDS) + precomputed
// bf16 bias table bias[i][j][h] = mask + rpe-sum. Main j-loop scalar reads
// go 5 -> 1 (the LDS-instruction bottleneck identified in rounds 8-10).
// mask/rel_pos read from global during precompute (off the LDS pipe).

static constexpr int NWIN = 4096;
static constexpr int MROWS = NWIN * 33;          // 135168 = 1056*128
static constexpr float SCALE = 0.25f;            // HD^-0.5

using short8 = __attribute__((ext_vector_type(8))) short;
using f32x4  = __attribute__((ext_vector_type(4))) float;

__device__ __forceinline__ unsigned short f2bf(float f) {
  unsigned u = __float_as_uint(f);
  u += 0x7fffu + ((u >> 16) & 1u);
  return (unsigned short)(u >> 16);
}
__device__ __forceinline__ float bf2f(unsigned short h) {
  return __uint_as_float(((unsigned)h) << 16);
}
__device__ __forceinline__ float bflo(unsigned u) { return __uint_as_float(u << 16); }
__device__ __forceinline__ float bfhi(unsigned u) { return __uint_as_float(u & 0xffff0000u); }
__device__ __forceinline__ float dot4(const float4 a, const float4 b) {
  return a.x*b.x + a.y*b.y + a.z*b.z + a.w*b.w;
}
__device__ __forceinline__ void axpy4(float4& o, const float a, const float4 v) {
  o.x += a*v.x; o.y += a*v.y; o.z += a*v.z; o.w += a*v.w;
}

// ---------------- K0: qkv_w -> B-fragments in d_out ----------------
__global__ __launch_bounds__(256) void conv_w_qkv(
    const float* __restrict__ W, unsigned* __restrict__ frag) {
  const int fp = blockIdx.x;                     // 108 = 3 ksteps*18 cf*2 hl
  const int kstep = fp / 36;
  const int r = fp - kstep*36;
  const int cf = r >> 1, hl = r & 1;
  const int t = threadIdx.x, lane = t >> 2, d = t & 3;
  const int k = kstep*32 + (lane >> 4)*8 + d*2;
  const int n = cf*16 + (lane & 15);
  float w0 = W[k*288 + n], w1 = W[(k+1)*288 + n];
  if (hl) { w0 -= bf2f(f2bf(w0)); w1 -= bf2f(f2bf(w1)); }
  frag[fp*256 + t] = (unsigned)f2bf(w0) | ((unsigned)f2bf(w1) << 16);
}

// ---------------- K2b: proj_w -> B-fragments at start of (dead) kvh ----
__global__ __launch_bounds__(256) void conv_w_proj(
    const float* __restrict__ W, unsigned* __restrict__ frag) {
  const int fp = blockIdx.x;                     // 36 = 3 ksteps*6 cf*2 hl
  const int kstep = fp / 12;
  const int r = fp - kstep*12;
  const int cf = r >> 1, hl = r & 1;
  const int t = threadIdx.x, lane = t >> 2, d = t & 3;
  const int k = kstep*32 + (lane >> 4)*8 + d*2;
  const int n = cf*16 + (lane & 15);
  float w0 = W[k*96 + n], w1 = W[(k+1)*96 + n];
  if (hl) { w0 -= bf2f(f2bf(w0)); w1 -= bf2f(f2bf(w1)); }
  frag[fp*256 + t] = (unsigned)f2bf(w0) | ((unsigned)f2bf(w1) << 16);
}

// ---------------- K1: QKV projection, split-bf16 MFMA ----------------
// grid (1056, 3), block 256 (4 waves). s: 0=q (fp32 out), 1=k, 2=v (bf16 out).
__global__ __launch_bounds__(256) void qkv_mfma(
    const float* __restrict__ A, const unsigned* __restrict__ frag,
    const float* __restrict__ bias, float* __restrict__ qf,
    unsigned short* __restrict__ kvh) {
  __shared__ __align__(16) unsigned short sAh[128*104];
  __shared__ __align__(16) unsigned short sAl[128*104];
  const int tid = threadIdx.x;
  const int w = tid >> 6, l = tid & 63;
  const int m0 = blockIdx.x * 128;
  const int s = blockIdx.y;
  for (int idx = tid; idx < 3072; idx += 256) {
    const int row = idx / 24, q = idx - row*24;
    const float4 v = *(const float4*)(A + (size_t)(m0+row)*96 + q*4);
    ushort4 hv, lv;
    hv.x = f2bf(v.x); hv.y = f2bf(v.y); hv.z = f2bf(v.z); hv.w = f2bf(v.w);
    lv.x = f2bf(v.x - bf2f(hv.x)); lv.y = f2bf(v.y - bf2f(hv.y));
    lv.z = f2bf(v.z - bf2f(hv.z)); lv.w = f2bf(v.w - bf2f(hv.w));
    *(ushort4*)&sAh[row*104 + q*4] = hv;
    *(ushort4*)&sAl[row*104 + q*4] = lv;
  }
  __syncthreads();
  f32x4 acc[2][6];
  #pragma unroll
  for (int rf = 0; rf < 2; ++rf)
    #pragma unroll
    for (int cf = 0; cf < 6; ++cf) acc[rf][cf] = (f32x4){0.f,0.f,0.f,0.f};

  #pragma unroll
  for (int kstep = 0; kstep < 3; ++kstep) {
    short8 bh[6], bl[6];
    #pragma unroll
    for (int cf = 0; cf < 6; ++cf) {
      const int fp = (kstep*18 + s*6 + cf)*2;
      bh[cf] = *(const short8*)((const char*)frag + (size_t)fp*1024 + l*16);
      bl[cf] = *(const short8*)((const char*)frag + (size_t)fp*1024 + 1024 + l*16);
    }
    #pragma unroll
    for (int rf = 0; rf < 2; ++rf) {
      const int row = w*32 + rf*16 + (l & 15);
      const int off = row*104 + kstep*32 + (l >> 4)*8;
      const short8 ah = *(const short8*)&sAh[off];
      const short8 al = *(const short8*)&sAl[off];
      #pragma unroll
      for (int cf = 0; cf < 6; ++cf) {
        acc[rf][cf] = __builtin_amdgcn_mfma_f32_16x16x32_bf16(ah, bh[cf], acc[rf][cf], 0,0,0);
        acc[rf][cf] = __builtin_amdgcn_mfma_f32_16x16x32_bf16(al, bh[cf], acc[rf][cf], 0,0,0);
        acc[rf][cf] = __builtin_amdgcn_mfma_f32_16x16x32_bf16(ah, bl[cf], acc[rf][cf], 0,0,0);
      }
    }
  }
  const int col = l & 15;
  if (s == 0) {
    #pragma unroll
    for (int cf = 0; cf < 6; ++cf) {
      const float bv = bias[cf*16 + col];
      #pragma unroll
      for (int rf = 0; rf < 2; ++rf)
        #pragma unroll
        for (int r = 0; r < 4; ++r) {
          const int m = m0 + w*32 + rf*16 + (l >> 4)*4 + r;
          const int n = m / 33, t = m - n*33;
          qf[(size_t)n*3168 + cf*528 + t*16 + col] = (acc[rf][cf][r] + bv)*SCALE;
        }
    }
  } else {
    unsigned short* kvs = kvh + (size_t)(s-1)*3168;
    #pragma unroll
    for (int cf = 0; cf < 6; ++cf) {
      const float bv = bias[s*96 + cf*16 + col];
      #pragma unroll
      for (int rf = 0; rf < 2; ++rf)
        #pragma unroll
        for (int r = 0; r < 4; ++r) {
          const int m = m0 + w*32 + rf*16 + (l >> 4)*4 + r;
          const int n = m / 33, t = m - n*33;
          kvs[(size_t)n*6336 + cf*528 + t*16 + col] = f2bf(acc[rf][cf][r] + bv);
        }
    }
  }
}

// ---------------- K2: per-window attention (v10, bias table) ----------
// grid 4096, block 256; thread = (head,row), 198 active.
// Phase 1: stage K,V fp32 + rpe bf16 [153][6]. Phase 2: bias[i][j][h] =
// mask + rpe-sum (bf16, 13.1 KB); mask/rel read from GLOBAL here.
// Phase 3: v7 main loop, 1 bias read per j (was 5 scalar LDS reads).
__global__ __launch_bounds__(256) void attn_kernel(
    float* __restrict__ qf, const unsigned short* __restrict__ kvh,
    const int* __restrict__ rel, const float* __restrict__ mask,
    const float* __restrict__ rpet) {
  __shared__ __align__(16) float sKf[3168];             // 12672 B
  __shared__ __align__(16) float sVf[3168];             // 12672 B
  __shared__ __align__(4) unsigned short sBias[1089*6]; // 13068 B
  __shared__ __align__(4) unsigned short sRpe6[918];    //  1836 B
  const int tid = threadIdx.x;
  const int n = blockIdx.x;
  const uint4* kvb = (const uint4*)(kvh + (size_t)n*6336);
  // phase 1: K and V (396 uint4 each) bf16 -> fp32; rpe table -> bf16
  for (int idx = tid; idx < 396; idx += 256) {
    const uint4 u = kvb[idx];
    float4 a, b;
    a.x = bflo(u.x); a.y = bfhi(u.x); a.z = bflo(u.y); a.w = bfhi(u.y);
    b.x = bflo(u.z); b.y = bfhi(u.z); b.z = bflo(u.w); b.w = bfhi(u.w);
    *(float4*)&sKf[idx*8]     = a;
    *(float4*)&sKf[idx*8 + 4] = b;
    const uint4 w = kvb[396 + idx];
    float4 c, d;
    c.x = bflo(w.x); c.y = bfhi(w.x); c.z = bflo(w.y); c.w = bfhi(w.y);
    d.x = bflo(w.z); d.y = bfhi(w.z); d.z = bflo(w.w); d.w = bfhi(w.w);
    *(float4*)&sVf[idx*8]     = c;
    *(float4*)&sVf[idx*8 + 4] = d;
  }
  for (int idx = tid; idx < 918; idx += 256)
    sRpe6[idx] = f2bf(rpet[idx]);
  __syncthreads();
  // phase 2: bias table (all 6 heads per entry via packed dword reads)
  {
    const float* gm = mask + (size_t)n*1089;
    const int*   rb = rel  + (size_t)n*3072;
    const unsigned* rp6 = (const unsigned*)sRpe6;  // [153] rows of 3 dwords
    unsigned* bw = (unsigned*)sBias;
    for (int e = tid; e < 1089; e += 256) {
      const int i = e / 33, j = e - i*33;
      const float mv = gm[e];
      float b0=mv, b1=mv, b2=mv, b3=mv, b4=mv, b5=mv;
      if (i > 0 && j > 0) {
        const int rbase = ((i-1)*32 + (j-1))*3;
        const int x0 = rb[rbase]*3;            // idx*6 ushorts = idx*3 dwords
        const int x1 = (rb[rbase+1] + 51)*3;
        const int x2 = (rb[rbase+2] + 102)*3;
        unsigned u;
        u = rp6[x0];   b0 += bflo(u); b1 += bfhi(u);
        u = rp6[x0+1]; b2 += bflo(u); b3 += bfhi(u);
        u = rp6[x0+2]; b4 += bflo(u); b5 += bfhi(u);
        u = rp6[x1];   b0 += bflo(u); b1 += bfhi(u);
        u = rp6[x1+1]; b2 += bflo(u); b3 += bfhi(u);
        u = rp6[x1+2]; b4 += bflo(u); b5 += bfhi(u);
        u = rp6[x2];   b0 += bflo(u); b1 += bfhi(u);
        u = rp6[x2+1]; b2 += bflo(u); b3 += bfhi(u);
        u = rp6[x2+2]; b4 += bflo(u); b5 += bfhi(u);
      }
      bw[e*3+0] = (unsigned)f2bf(b0) | ((unsigned)f2bf(b1) << 16);
      bw[e*3+1] = (unsigned)f2bf(b2) | ((unsigned)f2bf(b3) << 16);
      bw[e*3+2] = (unsigned)f2bf(b4) | ((unsigned)f2bf(b5) << 16);
    }
  }
  float4 q0, q1, q2, q3;
  int h = 0, i = 0;
  if (tid < 198) {
    h = tid / 33; i = tid - h*33;
    const float4* qb = (const float4*)(qf + (size_t)n*3168 + h*528 + i*16);
    q0 = qb[0]; q1 = qb[1]; q2 = qb[2]; q3 = qb[3];   // q read BEFORE barrier
  }
  __syncthreads();
  if (tid < 198) {
    const unsigned short* bp = sBias + i*198 + h;     // (i*33+j)*6+h
    float p[33];
    float mx = -3.4e38f;
    #pragma unroll
    for (int j = 0; j < 33; ++j) {
      const float4* kr = (const float4*)&sKf[(h*33 + j)*16];
      float lo = dot4(q0,kr[0]) + dot4(q1,kr[1]) + dot4(q2,kr[2]) + dot4(q3,kr[3]);
      lo += bf2f(bp[j*6]);
      p[j] = lo;
      mx = fmaxf(mx, lo);
    }
    float ssum = 0.f;
    #pragma unroll
    for (int j = 0; j < 33; ++j) { p[j] = __expf(p[j] - mx); ssum += p[j]; }
    const float inv = 1.0f / ssum;
    float4 o0 = make_float4(0.f,0.f,0.f,0.f), o1 = o0, o2 = o0, o3 = o0;
    #pragma unroll
    for (int j = 0; j < 33; ++j) {
      const float pj = p[j];
      const float4* vr = (const float4*)&sVf[(h*33 + j)*16];
      axpy4(o0, pj, vr[0]); axpy4(o1, pj, vr[1]);
      axpy4(o2, pj, vr[2]); axpy4(o3, pj, vr[3]);
    }
    o0.x*=inv; o0.y*=inv; o0.z*=inv; o0.w*=inv;
    o1.x*=inv; o1.y*=inv; o1.z*=inv; o1.w*=inv;
    o2.x*=inv; o2.y*=inv; o2.z*=inv; o2.w*=inv;
    o3.x*=inv; o3.y*=inv; o3.z*=inv; o3.w*=inv;
    float* op = qf + (size_t)n*3168 + (size_t)i*96 + h*16;
    *(float4*)(op + 0)  = o0; *(float4*)(op + 4)  = o1;
    *(float4*)(op + 8)  = o2; *(float4*)(op + 12) = o3;
  }
}

// ---------------- K3: output projection, split-bf16 MFMA ----------------
// grid 1056, block 256. A = attn output in qf; B-frags at start of kvh.
__global__ __launch_bounds__(256) void proj_mfma(
    const float* __restrict__ qf, const unsigned* __restrict__ frag,
    const float* __restrict__ bias, float* __restrict__ out) {
  __shared__ __align__(16) unsigned short sAh[128*104];
  __shared__ __align__(16) unsigned short sAl[128*104];
  const int tid = threadIdx.x;
  const int w = tid >> 6, l = tid & 63;
  const int m0 = blockIdx.x * 128;
  for (int idx = tid; idx < 3072; idx += 256) {
    const int row = idx / 24, q = idx - row*24;
    const int m = m0 + row;
    const int n = m / 33, t = m - n*33;
    const float4 v = *(const float4*)(qf + (size_t)n*3168 + t*96 + q*4);
    ushort4 hv, lv;
    hv.x = f2bf(v.x); hv.y = f2bf(v.y); hv.z = f2bf(v.z); hv.w = f2bf(v.w);
    lv.x = f2bf(v.x - bf2f(hv.x)); lv.y = f2bf(v.y - bf2f(hv.y));
    lv.z = f2bf(v.z - bf2f(hv.z)); lv.w = f2bf(v.w - bf2f(hv.w));
    *(ushort4*)&sAh[row*104 + q*4] = hv;
    *(ushort4*)&sAl[row*104 + q*4] = lv;
  }
  __syncthreads();
  f32x4 acc[2][6];
  #pragma unroll
  for (int rf = 0; rf < 2; ++rf)
    #pragma unroll
    for (int cf = 0; cf < 6; ++cf) acc[rf][cf] = (f32x4){0.f,0.f,0.f,0.f};

  #pragma unroll
  for (int kstep = 0; kstep < 3; ++kstep) {
    short8 bh[6], bl[6];
    #pragma unroll
    for (int cf = 0; cf < 6; ++cf) {
      const int fph = kstep*12 + cf*2;
      bh[cf] = *(const short8*)(frag + fph*256 + l*4);
      bl[cf] = *(const short8*)(frag + (fph+1)*256 + l*4);
    }
    #pragma unroll
    for (int rf = 0; rf < 2; ++rf) {
      const int row = w*32 + rf*16 + (l & 15);
      const int off = row*104 + kstep*32 + (l >> 4)*8;
      const short8 ah = *(const short8*)&sAh[off];
      const short8 al = *(const short8*)&sAl[off];
      #pragma unroll
      for (int cf = 0; cf < 6; ++cf) {
        acc[rf][cf] = __builtin_amdgcn_mfma_f32_16x16x32_bf16(ah, bh[cf], acc[rf][cf], 0,0,0);
        acc[rf][cf] = __builtin_amdgcn_mfma_f32_16x16x32_bf16(al, bh[cf], acc[rf][cf], 0,0,0);
        acc[rf][cf] = __builtin_amdgcn_mfma_f32_16x16x32_bf16(ah, bl[cf], acc[rf][cf], 0,0,0);
      }
    }
  }
  const int col = l & 15;
  #pragma unroll
  for (int cf = 0; cf < 6; ++cf) {
    const float bv = bias[cf*16 + col];
    #pragma unroll
    for (int rf = 0; rf < 2; ++rf)
      #pragma unroll
      for (int r = 0; r < 4; ++r) {
        const int m = m0 + w*32 + rf*16 + (l >> 4)*4 + r;
        out[(size_t)m*96 + cf*16 + col] = acc[rf][cf][r] + bv;
      }
  }
}

extern "C" void kernel_launch(void* const* d_in, const int* in_sizes, int n_in,
                              void* d_out, int out_size, void* d_ws, size_t ws_size,
                              hipStream_t stream) {
  const float* data   = (const float*)d_in[0];
  const int*   rel    = (const int*)  d_in[1];
  const float* mask   = (const float*)d_in[2];
  const float* qkv_w  = (const float*)d_in[3];
  const float* qkv_b  = (const float*)d_in[4];
  const float* proj_w = (const float*)d_in[5];
  const float* proj_b = (const float*)d_in[6];
  const float* rpet   = (const float*)d_in[7];
  float* qf = (float*)d_ws;                              // 51.9 MB
  unsigned short* kvh = (unsigned short*)(qf + (size_t)NWIN*3168);  // 51.9 MB
  float* out = (float*)d_out;

  conv_w_qkv <<<dim3(108),         256, 0, stream>>>(qkv_w, (unsigned*)d_out);
  qkv_mfma   <<<dim3(MROWS/128,3), 256, 0, stream>>>(data, (const unsigned*)d_out, qkv_b, qf, kvh);
  attn_kernel<<<dim3(NWIN),        256, 0, stream>>>(qf, kvh, rel, mask, rpet);
  conv_w_proj<<<dim3(36),          256, 0, stream>>>(proj_w, (unsigned*)kvh);
  proj_mfma  <<<dim3(MROWS/128),   256, 0, stream>>>(qf, (const unsigned*)kvh, proj_b, out);
}